// Round 4
// baseline (10204.477 us; speedup 1.0000x reference)
//
#include <hip/hip_runtime.h>

typedef unsigned int u32;
typedef unsigned short u16;

#define NFR 8
#define NBX 1024
#define NTOT 8192     // 8*1024
#define NROW 7168     // 7*1024 adjacency rows
#define MAXS 48
#define NEGV -1000000000.0f
#define TSENT -3.0e38f

// Exact predicate IoU(a,b) >= 0.2 in f32, _rn ops in the reference's
// association order so -ffp-contract cannot change any compare vs numpy.
// LINKAGE_T == IOU_T == 0.2, so one predicate serves both uses.
__device__ __forceinline__ bool iou_ge(float4 a, float4 b) {
    float wx = fmaxf(__fsub_rn(fminf(a.z, b.z), fmaxf(a.x, b.x)), 0.0f);
    float wy = fmaxf(__fsub_rn(fminf(a.w, b.w), fmaxf(a.y, b.y)), 0.0f);
    float inter = __fmul_rn(wx, wy);
    if (!(inter > 0.0f)) return false;      // iou == 0 can never pass >= 0.2
    float aa = __fmul_rn(__fsub_rn(a.z, a.x), __fsub_rn(a.w, a.y));
    float ab = __fmul_rn(__fsub_rn(b.z, b.x), __fsub_rn(b.w, b.y));
    float den = __fadd_rn(__fsub_rn(__fadd_rn(aa, ab), inter), 1e-8f);
    return __fdiv_rn(inter, den) >= 0.2f;
}

// out = scores (identity part of the reference output), fully parallel.
__global__ __launch_bounds__(256) void copy_scores(const float* __restrict__ s,
                                                   float* __restrict__ o) {
    int i = blockIdx.x * 256 + threadIdx.x;
    o[i] = s[i];
}

// One block, 256 threads, static LDS ~63.2 KB (< 64 KB), no workspace.
__global__ __launch_bounds__(256) void seqnms256(const float4* __restrict__ gbox,
                                                 const float* __restrict__ scores,
                                                 const int* __restrict__ classes,
                                                 float* __restrict__ out) {
    __shared__ float ms[NTOT];          // 32768 B
    __shared__ u32 csr[NROW];           // 28672 B: [30:32)=cnt, 3x10-bit j;
                                        //   cnt==3 && j0==j1 -> overflow (rescan)
    __shared__ u32 clsb[NFR][3][32];    // 3072 B: class bitplanes per frame
    __shared__ float redv[4];
    __shared__ int   redi[4];
    __shared__ int   sel_sh[NFR];
    __shared__ float4 seqbox[NFR];
    __shared__ int   seqcls[NFR];
    __shared__ float bestval_sh, avg_sh;
    __shared__ int   fstar_sh, istar_sh, valid_sh, done_sh;

    const int t = threadIdx.x;
    if (t == 0) done_sh = 0;

    // ---- class bitplanes: one (frame, word) per thread (8*32 == 256) ----
    {
        int f = t >> 5, w = t & 31;
        u32 p0 = 0, p1 = 0, p2 = 0;
        for (int b = 0; b < 32; ++b) {
            int cl = classes[f * NBX + w * 32 + b];
            p0 |= (u32)(cl & 1) << b;
            p1 |= (u32)((cl >> 1) & 1) << b;
            p2 |= (u32)((cl >> 2) & 1) << b;
        }
        clsb[f][0][w] = p0; clsb[f][1][w] = p1; clsb[f][2][w] = p2;
    }
    __syncthreads();

    // ---- build packed CSR: 28 rows per thread; neighbors found in ascending
    //      j order (word asc, bit asc), needed for argmax tie-breaks ----
    for (int r = t; r < NROW; r += 256) {
        int f = r >> 10;
        int ca = classes[r];
        float4 a4 = gbox[r];
        u32 cnt = 0, j0 = 0, j1 = 0, j2 = 0;
        bool ovf = false;
        for (int w = 0; w < 32; ++w) {
            u32 p0 = clsb[f + 1][0][w], p1 = clsb[f + 1][1][w], p2 = clsb[f + 1][2][w];
            u32 m = ((ca & 1) ? p0 : ~p0) & ((ca & 2) ? p1 : ~p1) & ((ca & 4) ? p2 : ~p2);
            while (m) {
                int b = __ffs(m) - 1;
                m &= m - 1;
                int j = w * 32 + b;
                if (iou_ge(a4, gbox[(f + 1) * NBX + j])) {
                    if (cnt == 0) j0 = j; else if (cnt == 1) j1 = j;
                    else if (cnt == 2) j2 = j; else ovf = true;
                    ++cnt;
                }
            }
        }
        csr[r] = ovf ? (3u << 30)                                    // j0==j1==0 flag
                     : ((cnt << 30) | (j2 << 20) | (j1 << 10) | j0);
    }
    u32 act = 0xFFFFFFFFu;   // bit (k*8 + f) = active(f, t + 256k)
    __syncthreads();

    // ---- 48 greedy extractions. Invariant: active(f,i) <=> ms[f][i] != NEGV,
    //      and active => ms >= 0 (scores >= 0, best_succ >= 0 inductively). ----
    for (int it = 0; it < MAXS; ++it) {
        for (int k = 0; k < 4; ++k) {                    // DP init, frame 7
            int r = 7 * NBX + t + 256 * k;
            ms[r] = ((act >> (k * 8 + 7)) & 1) ? scores[r] : NEGV;
        }
        __syncthreads();
        for (int f = 6; f >= 0; --f) {                   // backward sweep
            const float* msn = &ms[(f + 1) * NBX];
            for (int k = 0; k < 4; ++k) {
                int r = f * NBX + t + 256 * k;
                float v = NEGV;
                if ((act >> (k * 8 + f)) & 1) {
                    float best = 0.0f;   // == ref max(where(eff, ms_next, 0))
                    u32 p = csr[r];
                    u32 cnt = p >> 30;
                    bool ovf = (cnt == 3) && ((p & 1023) == ((p >> 10) & 1023));
                    if (!ovf) {
                        if (cnt >= 1) best = fmaxf(best, fmaxf(msn[p & 1023], 0.0f));
                        if (cnt >= 2) best = fmaxf(best, fmaxf(msn[(p >> 10) & 1023], 0.0f));
                        if (cnt >= 3) best = fmaxf(best, fmaxf(msn[(p >> 20) & 1023], 0.0f));
                    } else {             // exact rescan over same-class candidates
                        int ca = classes[r];
                        float4 a4 = gbox[r];
                        for (int w = 0; w < 32; ++w) {
                            u32 p0 = clsb[f + 1][0][w], p1 = clsb[f + 1][1][w], p2 = clsb[f + 1][2][w];
                            u32 m = ((ca & 1) ? p0 : ~p0) & ((ca & 2) ? p1 : ~p1) & ((ca & 4) ? p2 : ~p2);
                            while (m) {
                                int b = __ffs(m) - 1;
                                m &= m - 1;
                                int j = w * 32 + b;
                                float mv = msn[j];
                                if (mv > 0.0f && iou_ge(a4, gbox[(f + 1) * NBX + j]))
                                    best = fmaxf(best, mv);
                            }
                        }
                    }
                    v = __fadd_rn(scores[r], best);
                }
                ms[r] = v;               // frame f written; reads were frame f+1
            }
            __syncthreads();
        }

        // ---- flat argmax over ms, first-index tie-break (== np.argmax) ----
        float bv = ms[t];
        int bi = t;
        for (int f = 0; f < NFR; ++f)
            for (int k = 0; k < 4; ++k) {
                if (f == 0 && k == 0) continue;
                int idx = f * NBX + t + 256 * k;
                float m = ms[idx];
                if (m > bv) { bv = m; bi = idx; }        // per-thread idx asc -> first wins
            }
        for (int off = 32; off > 0; off >>= 1) {
            float ov = __shfl_down(bv, off);
            int   oi = __shfl_down(bi, off);
            if (ov > bv || (ov == bv && oi < bi)) { bv = ov; bi = oi; }
        }
        if ((t & 63) == 0) { redv[t >> 6] = bv; redi[t >> 6] = bi; }
        if (t < NFR) sel_sh[t] = -1;
        __syncthreads();
        if (t == 0) {
            float v = redv[0]; int i0 = redi[0];
            for (int w = 1; w < 4; ++w)
                if (redv[w] > v || (redv[w] == v && redi[w] < i0)) { v = redv[w]; i0 = redi[w]; }
            bestval_sh = v;
            fstar_sh = i0 >> 10;
            istar_sh = i0 & (NBX - 1);
        }
        __syncthreads();

        // ---- traceback on wave 0 (all breaks wave-uniform) ----
        if (t < 64) {
            int cur = istar_sh;
            for (int f = fstar_sh; f < NFR; ++f) {
                if (t == 0) sel_sh[f] = cur;
                if (f == 7) break;                    // adj_pad[7] all-zero
                int r = f * NBX + cur;
                u32 p = csr[r];
                u32 cnt = p >> 30;
                bool ovf = (cnt == 3) && ((p & 1023) == ((p >> 10) & 1023));
                const float* msn = &ms[(f + 1) * NBX];
                float tv = TSENT;
                int tj = 1 << 30;
                if (!ovf) {
                    if (t < (int)cnt) {
                        int j = (p >> (10 * t)) & 1023;
                        float m = msn[j];
                        if (m != NEGV) { tv = m; tj = j; }   // m != NEGV <=> act_next
                    }
                } else if (t < 32) {
                    int ca = classes[r];
                    float4 a4 = gbox[r];
                    u32 p0 = clsb[f + 1][0][t], p1 = clsb[f + 1][1][t], p2 = clsb[f + 1][2][t];
                    u32 m = ((ca & 1) ? p0 : ~p0) & ((ca & 2) ? p1 : ~p1) & ((ca & 4) ? p2 : ~p2);
                    while (m) {
                        int b = __ffs(m) - 1;
                        m &= m - 1;
                        int j = t * 32 + b;
                        float mv = msn[j];
                        if (mv != NEGV && iou_ge(a4, gbox[(f + 1) * NBX + j])) {
                            if (mv > tv || (mv == tv && j < tj)) { tv = mv; tj = j; }
                        }
                    }
                }
                for (int off = 32; off > 0; off >>= 1) {
                    float ov = __shfl_down(tv, off);
                    int   oj = __shfl_down(tj, off);
                    if (ov > tv || (ov == tv && oj < tj)) { tv = ov; tj = oj; }
                }
                tv = __shfl(tv, 0);
                tj = __shfl(tj, 0);
                if (tv < -1.0e37f) break;             // no adj&active succ <=> !has_link
                cur = tj;
            }
        }
        __syncthreads();

        // ---- sequence stats ----
        if (t < NFR) {
            int sj = sel_sh[t];
            if (sj >= 0) {
                seqbox[t] = gbox[t * NBX + sj];
                seqcls[t] = classes[t * NBX + sj];
            }
        }
        if (t == 0) {
            int len = 0;
            float sum = 0.0f;
            for (int f = 0; f < NFR; ++f) {
                int sj = sel_sh[f];
                if (sj >= 0) { ++len; sum = __fadd_rn(sum, scores[f * NBX + sj]); }
            }
            avg_sh = __fdiv_rn(sum, (float)len);      // len >= 1 always
            bool ok = (len > 1) && (bestval_sh > 0.0f);
            valid_sh = (ok && !done_sh) ? 1 : 0;
            if (!ok) done_sh = 1;
        }
        __syncthreads();

        // ---- suppression + out writes (only when valid) ----
        if (valid_sh) {
            for (int f = 0; f < NFR; ++f) {
                int sj = sel_sh[f];
                if (sj < 0) continue;                 // frame_in false
                float4 s4 = seqbox[f];
                int scl = seqcls[f];
                float sa = __fmul_rn(__fsub_rn(s4.z, s4.x), __fsub_rn(s4.w, s4.y));
                for (int k = 0; k < 4; ++k) {
                    int c = t + 256 * k;
                    if (classes[f * NBX + c] != scl) continue;
                    float4 b4 = gbox[f * NBX + c];
                    float wx = fmaxf(__fsub_rn(fminf(s4.z, b4.z), fmaxf(s4.x, b4.x)), 0.0f);
                    float wy = fmaxf(__fsub_rn(fminf(s4.w, b4.w), fmaxf(s4.y, b4.y)), 0.0f);
                    float inter = __fmul_rn(wx, wy);
                    if (inter > 0.0f) {
                        float ba = __fmul_rn(__fsub_rn(b4.z, b4.x), __fsub_rn(b4.w, b4.y));
                        float den = __fadd_rn(__fsub_rn(__fadd_rn(sa, ba), inter), 1e-8f);
                        if (__fdiv_rn(inter, den) >= 0.2f) act &= ~(1u << (k * 8 + f));
                    }
                }
            }
            if (t < NFR) {
                int sj = sel_sh[t];
                if (sj >= 0) out[t * NBX + sj] = avg_sh;
            }
        }
        __syncthreads();
        if (done_sh) break;   // uniform; remaining reference iterations are no-ops
    }
}

extern "C" void kernel_launch(void* const* d_in, const int* in_sizes, int n_in,
                              void* d_out, int out_size, void* d_ws, size_t ws_size,
                              hipStream_t stream) {
    const float4* boxes = (const float4*)d_in[0];     // (8,1024,4) float32
    const float* scores = (const float*)d_in[1];      // (8,1024) float32
    const int* classes = (const int*)d_in[2];         // (8,1024) int32
    float* out = (float*)d_out;                       // (8,1024) float32

    copy_scores<<<32, 256, 0, stream>>>(scores, out);
    seqnms256<<<1, 256, 0, stream>>>(boxes, scores, classes, out);
}

// Round 5
// 2688.546 us; speedup vs baseline: 3.7955x; 3.7955x over previous
//
#include <hip/hip_runtime.h>

typedef unsigned int u32;
typedef unsigned short u16;

#define NFR 8
#define NBX 1024
#define NTOT 8192     // 8*1024
#define NROW 7168     // 7*1024 adjacency rows
#define MAXS 48
#define NEGV -1000000000.0f
#define TSENT -3.0e38f
#define SENTF 3.0e38f   // "active overflow row, resolve in phase B" marker
#define OVCAP 34        // per-frame overflow-list capacity

// Exact predicate IoU(a,b) >= 0.2 in f32, _rn ops in the reference's
// association order so -ffp-contract cannot change any compare vs numpy.
// LINKAGE_T == IOU_T == 0.2, so one predicate serves both uses.
__device__ __forceinline__ bool iou_ge(float4 a, float4 b) {
    float wx = fmaxf(__fsub_rn(fminf(a.z, b.z), fmaxf(a.x, b.x)), 0.0f);
    float wy = fmaxf(__fsub_rn(fminf(a.w, b.w), fmaxf(a.y, b.y)), 0.0f);
    float inter = __fmul_rn(wx, wy);
    if (!(inter > 0.0f)) return false;      // iou == 0 can never pass >= 0.2
    float aa = __fmul_rn(__fsub_rn(a.z, a.x), __fsub_rn(a.w, a.y));
    float ab = __fmul_rn(__fsub_rn(b.z, b.x), __fsub_rn(b.w, b.y));
    float den = __fadd_rn(__fsub_rn(__fadd_rn(aa, ab), inter), 1e-8f);
    return __fdiv_rn(inter, den) >= 0.2f;
}

// out = scores (identity part of the reference output), fully parallel.
__global__ __launch_bounds__(256) void copy_scores(const float* __restrict__ s,
                                                   float* __restrict__ o) {
    int i = blockIdx.x * 256 + threadIdx.x;
    o[i] = s[i];
}

// One block, 256 threads, static LDS < 64 KB, no workspace.
__global__ __launch_bounds__(256) void seqnms256(const float4* __restrict__ gbox,
                                                 const float* __restrict__ scores,
                                                 const int* __restrict__ classes,
                                                 float* __restrict__ out) {
    __shared__ float ms[NTOT];          // 32768 B
    __shared__ u32 csr[NROW];           // 28672 B: [30:32)=cnt, 3x10-bit j.
                                        //  cnt==3 && j0==j1==0 -> overflow, listed
                                        //  cnt==3 && j0==j1==1 -> overflow, unlisted (rescan)
    __shared__ u32 clsb7[7][3][32];     // 2688 B: class bitplanes, frames 1..7 (index f = frame-1... stored as clsb7[f] for pair f->f+1)
    __shared__ u16 ovl[7][OVCAP];       // 476 B: overflow row ids (i only; frame implicit)
    __shared__ u32 ocnt[7];             // 28 B
    __shared__ float redv[4];
    __shared__ int   redi[4];
    __shared__ int   sel_sh[NFR];
    __shared__ float4 seqbox[NFR];
    __shared__ int   seqcls[NFR];
    __shared__ float bestval_sh, avg_sh;
    __shared__ int   fstar_sh, istar_sh, valid_sh, done_sh;

    const int t = threadIdx.x;
    if (t == 0) done_sh = 0;
    if (t < 7) ocnt[t] = 0;

    // ---- class bitplanes for frames 1..7: one (frame, word) per thread ----
    if (t < 224) {
        int fr = (t >> 5) + 1, w = t & 31;
        u32 p0 = 0, p1 = 0, p2 = 0;
        for (int b = 0; b < 32; ++b) {
            int cl = classes[fr * NBX + w * 32 + b];
            p0 |= (u32)(cl & 1) << b;
            p1 |= (u32)((cl >> 1) & 1) << b;
            p2 |= (u32)((cl >> 2) & 1) << b;
        }
        clsb7[fr - 1][0][w] = p0; clsb7[fr - 1][1][w] = p1; clsb7[fr - 1][2][w] = p2;
    }
    __syncthreads();

    // ---- build packed CSR (28 rows/thread); neighbors in ascending j order ----
    for (int r = t; r < NROW; r += 256) {
        int f = r >> 10;
        int ca = classes[r];
        float4 a4 = gbox[r];
        u32 cnt = 0, j0 = 0, j1 = 0, j2 = 0;
        for (int w = 0; w < 32; ++w) {
            u32 p0 = clsb7[f][0][w], p1 = clsb7[f][1][w], p2 = clsb7[f][2][w];
            u32 m = ((ca & 1) ? p0 : ~p0) & ((ca & 2) ? p1 : ~p1) & ((ca & 4) ? p2 : ~p2);
            while (m) {
                int b = __ffs(m) - 1;
                m &= m - 1;
                int j = w * 32 + b;
                if (iou_ge(a4, gbox[(f + 1) * NBX + j])) {
                    if (cnt == 0) j0 = j; else if (cnt == 1) j1 = j; else if (cnt == 2) j2 = j;
                    ++cnt;
                }
            }
        }
        if (cnt <= 3) {
            csr[r] = (cnt << 30) | (j2 << 20) | (j1 << 10) | j0;
        } else {
            u32 slot = atomicAdd(&ocnt[f], 1u);
            if (slot < OVCAP) { ovl[f][slot] = (u16)(r & (NBX - 1)); csr[r] = 3u << 30; }
            else               { csr[r] = (3u << 30) | (1u << 10) | 1u; }
        }
    }
    u32 act = 0xFFFFFFFFu;   // bit (k*8 + f) = active(f, t + 256k)
    __syncthreads();

    // ---- 48 greedy extractions. Invariant: active(f,i) <=> ms[f][i] != NEGV,
    //      and active => ms >= 0 (scores >= 0, best_succ >= 0 inductively). ----
    for (int it = 0; it < MAXS; ++it) {
        for (int k = 0; k < 4; ++k) {                    // DP init, frame 7
            int r = 7 * NBX + t + 256 * k;
            ms[r] = ((act >> (k * 8 + 7)) & 1) ? scores[r] : NEGV;
        }
        __syncthreads();
        for (int f = 6; f >= 0; --f) {                   // backward sweep
            const float* msn = &ms[(f + 1) * NBX];
            // phase A: inline rows resolved; listed overflow rows -> sentinel
            for (int k = 0; k < 4; ++k) {
                int r = f * NBX + t + 256 * k;
                float v = NEGV;
                if ((act >> (k * 8 + f)) & 1) {
                    u32 p = csr[r];
                    u32 cnt = p >> 30;
                    u32 pj0 = p & 1023, pj1 = (p >> 10) & 1023;
                    bool ovf = (cnt == 3) && (pj0 == pj1);
                    if (!ovf) {
                        float best = 0.0f;   // == ref max(where(eff, ms_next, 0))
                        if (cnt >= 1) best = fmaxf(best, fmaxf(msn[pj0], 0.0f));
                        if (cnt >= 2) best = fmaxf(best, fmaxf(msn[pj1], 0.0f));
                        if (cnt >= 3) best = fmaxf(best, fmaxf(msn[(p >> 20) & 1023], 0.0f));
                        v = __fadd_rn(scores[r], best);
                    } else if (pj0 == 0) {
                        v = SENTF;           // listed: wave-cooperative phase B
                    } else {                 // unlisted (list overran): exact rescan
                        float best = 0.0f;
                        int ca = classes[r];
                        float4 a4 = gbox[r];
                        for (int w = 0; w < 32; ++w) {
                            u32 p0 = clsb7[f][0][w], p1 = clsb7[f][1][w], p2 = clsb7[f][2][w];
                            u32 m = ((ca & 1) ? p0 : ~p0) & ((ca & 2) ? p1 : ~p1) & ((ca & 4) ? p2 : ~p2);
                            while (m) {
                                int b = __ffs(m) - 1;
                                m &= m - 1;
                                int j = w * 32 + b;
                                float mv = msn[j];
                                if (mv > 0.0f && iou_ge(a4, gbox[(f + 1) * NBX + j]))
                                    best = fmaxf(best, mv);
                            }
                        }
                        v = __fadd_rn(scores[r], best);
                    }
                }
                ms[r] = v;
            }
            __syncthreads();
            // phase B: each wave resolves listed overflow rows cooperatively
            {
                int wv = t >> 6, ln = t & 63;
                int nl = (int)ocnt[f]; if (nl > OVCAP) nl = OVCAP;
                for (int e = wv; e < nl; e += 4) {
                    int i = ovl[f][e];
                    int r = f * NBX + i;
                    if (ms[r] != SENTF) continue;        // inactive this iteration
                    int ca = classes[r];
                    float4 a4 = gbox[r];
                    float best = 0.0f;                   // identity of the ref max
                    if (ln < 32) {
                        u32 p0 = clsb7[f][0][ln], p1 = clsb7[f][1][ln], p2 = clsb7[f][2][ln];
                        u32 m = ((ca & 1) ? p0 : ~p0) & ((ca & 2) ? p1 : ~p1) & ((ca & 4) ? p2 : ~p2);
                        while (m) {
                            int b = __ffs(m) - 1;
                            m &= m - 1;
                            int j = ln * 32 + b;
                            float mv = msn[j];           // NEGV (inactive) -> clamps to 0
                            if (iou_ge(a4, gbox[(f + 1) * NBX + j]))
                                best = fmaxf(best, fmaxf(mv, 0.0f));
                        }
                    }
                    for (int off = 32; off > 0; off >>= 1)
                        best = fmaxf(best, __shfl_down(best, off));
                    if (ln == 0) ms[r] = __fadd_rn(scores[r], best);
                }
            }
            __syncthreads();
        }

        // ---- flat argmax over ms, first-index tie-break (== np.argmax) ----
        float bv = ms[t];
        int bi = t;
        for (int f = 0; f < NFR; ++f)
            for (int k = 0; k < 4; ++k) {
                if (f == 0 && k == 0) continue;
                int idx = f * NBX + t + 256 * k;
                float m = ms[idx];
                if (m > bv) { bv = m; bi = idx; }        // per-thread idx asc -> first wins
            }
        for (int off = 32; off > 0; off >>= 1) {
            float ov = __shfl_down(bv, off);
            int   oi = __shfl_down(bi, off);
            if (ov > bv || (ov == bv && oi < bi)) { bv = ov; bi = oi; }
        }
        if ((t & 63) == 0) { redv[t >> 6] = bv; redi[t >> 6] = bi; }
        if (t < NFR) sel_sh[t] = -1;
        __syncthreads();
        if (t == 0) {
            float v = redv[0]; int i0 = redi[0];
            for (int w = 1; w < 4; ++w)
                if (redv[w] > v || (redv[w] == v && redi[w] < i0)) { v = redv[w]; i0 = redi[w]; }
            bestval_sh = v;
            fstar_sh = i0 >> 10;
            istar_sh = i0 & (NBX - 1);
        }
        __syncthreads();

        // ---- traceback on wave 0 (all breaks wave-uniform) ----
        if (t < 64) {
            int cur = istar_sh;
            for (int f = fstar_sh; f < NFR; ++f) {
                if (t == 0) sel_sh[f] = cur;
                if (f == 7) break;                    // adj_pad[7] all-zero
                int r = f * NBX + cur;
                u32 p = csr[r];
                u32 cnt = p >> 30;
                bool ovf = (cnt == 3) && ((p & 1023) == ((p >> 10) & 1023));
                const float* msn = &ms[(f + 1) * NBX];
                float tv = TSENT;
                int tj = 1 << 30;
                if (!ovf) {
                    if (t < (int)cnt) {
                        int j = (p >> (10 * t)) & 1023;
                        float m = msn[j];
                        if (m != NEGV) { tv = m; tj = j; }   // m != NEGV <=> act_next
                    }
                } else if (t < 32) {
                    int ca = classes[r];
                    float4 a4 = gbox[r];
                    u32 p0 = clsb7[f][0][t], p1 = clsb7[f][1][t], p2 = clsb7[f][2][t];
                    u32 m = ((ca & 1) ? p0 : ~p0) & ((ca & 2) ? p1 : ~p1) & ((ca & 4) ? p2 : ~p2);
                    while (m) {
                        int b = __ffs(m) - 1;
                        m &= m - 1;
                        int j = t * 32 + b;
                        float mv = msn[j];
                        if (mv != NEGV && iou_ge(a4, gbox[(f + 1) * NBX + j])) {
                            if (mv > tv || (mv == tv && j < tj)) { tv = mv; tj = j; }
                        }
                    }
                }
                for (int off = 32; off > 0; off >>= 1) {
                    float ov = __shfl_down(tv, off);
                    int   oj = __shfl_down(tj, off);
                    if (ov > tv || (ov == tv && oj < tj)) { tv = ov; tj = oj; }
                }
                tv = __shfl(tv, 0);
                tj = __shfl(tj, 0);
                if (tv < -1.0e37f) break;             // no adj&active succ <=> !has_link
                cur = tj;
            }
        }
        __syncthreads();

        // ---- sequence stats ----
        if (t < NFR) {
            int sj = sel_sh[t];
            if (sj >= 0) {
                seqbox[t] = gbox[t * NBX + sj];
                seqcls[t] = classes[t * NBX + sj];
            }
        }
        if (t == 0) {
            int len = 0;
            float sum = 0.0f;
            for (int f = 0; f < NFR; ++f) {
                int sj = sel_sh[f];
                if (sj >= 0) { ++len; sum = __fadd_rn(sum, scores[f * NBX + sj]); }
            }
            avg_sh = __fdiv_rn(sum, (float)len);      // len >= 1 always
            bool ok = (len > 1) && (bestval_sh > 0.0f);
            valid_sh = (ok && !done_sh) ? 1 : 0;
            if (!ok) done_sh = 1;
        }
        __syncthreads();

        // ---- suppression + out writes (only when valid) ----
        if (valid_sh) {
            for (int f = 0; f < NFR; ++f) {
                int sj = sel_sh[f];
                if (sj < 0) continue;                 // frame_in false
                float4 s4 = seqbox[f];
                int scl = seqcls[f];
                float sa = __fmul_rn(__fsub_rn(s4.z, s4.x), __fsub_rn(s4.w, s4.y));
                for (int k = 0; k < 4; ++k) {
                    int c = t + 256 * k;
                    if (classes[f * NBX + c] != scl) continue;
                    float4 b4 = gbox[f * NBX + c];
                    float wx = fmaxf(__fsub_rn(fminf(s4.z, b4.z), fmaxf(s4.x, b4.x)), 0.0f);
                    float wy = fmaxf(__fsub_rn(fminf(s4.w, b4.w), fmaxf(s4.y, b4.y)), 0.0f);
                    float inter = __fmul_rn(wx, wy);
                    if (inter > 0.0f) {
                        float ba = __fmul_rn(__fsub_rn(b4.z, b4.x), __fsub_rn(b4.w, b4.y));
                        float den = __fadd_rn(__fsub_rn(__fadd_rn(sa, ba), inter), 1e-8f);
                        if (__fdiv_rn(inter, den) >= 0.2f) act &= ~(1u << (k * 8 + f));
                    }
                }
            }
            if (t < NFR) {
                int sj = sel_sh[t];
                if (sj >= 0) out[t * NBX + sj] = avg_sh;
            }
        }
        __syncthreads();
        if (done_sh) break;   // uniform; remaining reference iterations are no-ops
    }
}

extern "C" void kernel_launch(void* const* d_in, const int* in_sizes, int n_in,
                              void* d_out, int out_size, void* d_ws, size_t ws_size,
                              hipStream_t stream) {
    const float4* boxes = (const float4*)d_in[0];     // (8,1024,4) float32
    const float* scores = (const float*)d_in[1];      // (8,1024) float32
    const int* classes = (const int*)d_in[2];         // (8,1024) int32
    float* out = (float*)d_out;                       // (8,1024) float32

    copy_scores<<<32, 256, 0, stream>>>(scores, out);
    seqnms256<<<1, 256, 0, stream>>>(boxes, scores, classes, out);
}

// Round 6
// 1161.698 us; speedup vs baseline: 8.7841x; 2.3143x over previous
//
#include <hip/hip_runtime.h>

typedef unsigned int u32;
typedef unsigned short u16;
typedef unsigned char u8;

#define NFR 8
#define NBX 1024
#define NTOT 8192     // 8*1024
#define NROW 7168     // 7*1024 adjacency rows
#define MAXS 48
#define NEGV -1000000000.0f
#define TSENT -3.0e38f
#define SENTF 3.0e38f   // "active overflow row, resolve in phase B" marker
#define OVCAP 34        // per-frame overflow-list capacity
#define POOLCAP 4096    // u16 entries in the d_ws neighbor pool (8 KB)
#define RESCAN_ENC ((3u << 30) | (1023u << 10) | 1023u)

// Exact predicate IoU(a,b) >= 0.2 in f32, _rn ops in the reference's
// association order so -ffp-contract cannot change any compare vs numpy.
// LINKAGE_T == IOU_T == 0.2, so one predicate serves both uses.
__device__ __forceinline__ bool iou_ge(float4 a, float4 b) {
    float wx = fmaxf(__fsub_rn(fminf(a.z, b.z), fmaxf(a.x, b.x)), 0.0f);
    float wy = fmaxf(__fsub_rn(fminf(a.w, b.w), fmaxf(a.y, b.y)), 0.0f);
    float inter = __fmul_rn(wx, wy);
    if (!(inter > 0.0f)) return false;      // iou == 0 can never pass >= 0.2
    float aa = __fmul_rn(__fsub_rn(a.z, a.x), __fsub_rn(a.w, a.y));
    float ab = __fmul_rn(__fsub_rn(b.z, b.x), __fsub_rn(b.w, b.y));
    float den = __fadd_rn(__fsub_rn(__fadd_rn(aa, ab), inter), 1e-8f);
    return __fdiv_rn(inter, den) >= 0.2f;
}

// One block, 1024 threads (16 waves for latency hiding), LDS ~63.5 KB.
// csr encoding per row: [30:32)=cnt; cnt<=2 or (cnt==3, j0<j1<j2 strict): inline.
//   Overflow marker: cnt==3 && j0==j1 (impossible for legit ascending inline):
//     j0==j1==0            -> listed, no pool (phase-B IoU recompute path)
//     j0==j1==deg (4..1022)-> listed, pool: entries pool[off .. off+deg), off=((enc>>20)&1023)*4
//     j0==j1==1023         -> unlisted/failed alloc -> exact serial rescan in phase A
__global__ __launch_bounds__(1024) void seqnms1024(const float4* __restrict__ gbox,
                                                   const float* __restrict__ scores,
                                                   const int* __restrict__ classes,
                                                   float* __restrict__ out,
                                                   u16* __restrict__ pool,
                                                   const int use_pool) {
    __shared__ float ms[NTOT];          // 32768 B
    __shared__ u32 csr[NROW];           // 28672 B
    __shared__ u32 clsb7[7][3][32];     // 2688 B: class bitplanes, frames 1..7
    __shared__ u16 ovl[7][OVCAP];       // 476 B: listed overflow row ids
    __shared__ u32 ocnt[7];             // 28 B
    __shared__ u32 pool_top;            // 4 B
    __shared__ float redv[16];
    __shared__ int   redi[16];
    __shared__ int   sel_sh[NFR];
    __shared__ float4 seqbox[NFR];
    __shared__ int   seqcls[NFR];
    __shared__ float bestval_sh, avg_sh;
    __shared__ int   fstar_sh, istar_sh, valid_sh, done_sh;

    const int t = threadIdx.x;
    const int gw = t >> 6, ln = t & 63;
    if (t == 0) { done_sh = 0; pool_top = 0; }
    if (t < 7) ocnt[t] = 0;

    // out = scores (identity part of the reference output)
    for (int f = 0; f < NFR; ++f) out[f * NBX + t] = scores[f * NBX + t];

    // ---- class bitplanes for frames 1..7 ----
    if (t < 224) {
        int fr = (t >> 5) + 1, w = t & 31;
        u32 p0 = 0, p1 = 0, p2 = 0;
        for (int b = 0; b < 32; ++b) {
            int cl = classes[fr * NBX + w * 32 + b];
            p0 |= (u32)(cl & 1) << b;
            p1 |= (u32)((cl >> 1) & 1) << b;
            p2 |= (u32)((cl >> 2) & 1) << b;
        }
        clsb7[fr - 1][0][w] = p0; clsb7[fr - 1][1][w] = p1; clsb7[fr - 1][2][w] = p2;
    }
    __syncthreads();

    // ---- CSR pass 1: one row per (frame, column-t); ascending j order ----
    for (int f = 0; f < 7; ++f) {
        int r = f * NBX + t;
        int ca = classes[r];
        float4 a4 = gbox[r];
        u32 cnt = 0, j0 = 0, j1 = 0, j2 = 0;
        for (int w = 0; w < 32; ++w) {
            u32 p0 = clsb7[f][0][w], p1 = clsb7[f][1][w], p2 = clsb7[f][2][w];
            u32 m = ((ca & 1) ? p0 : ~p0) & ((ca & 2) ? p1 : ~p1) & ((ca & 4) ? p2 : ~p2);
            while (m) {
                int b = __ffs(m) - 1;
                m &= m - 1;
                int j = w * 32 + b;
                if (iou_ge(a4, gbox[(f + 1) * NBX + j])) {
                    if (cnt == 0) j0 = j; else if (cnt == 1) j1 = j; else if (cnt == 2) j2 = j;
                    ++cnt;
                }
            }
        }
        if (cnt <= 3) {
            csr[r] = (cnt << 30) | (j2 << 20) | (j1 << 10) | j0;
        } else {
            u32 slot = atomicAdd(&ocnt[f], 1u);
            if (slot < OVCAP) { ovl[f][slot] = (u16)t; csr[r] = 3u << 30; }  // listed
            else               csr[r] = RESCAN_ENC;
        }
    }
    __syncthreads();

    // ---- CSR pass 2 (pool build): one wave per listed row, ballot-compaction
    //      writes the FULL neighbor list to the d_ws pool in ascending j order ----
    if (use_pool) {
        for (int f = 0; f < 7; ++f) {
            int nl = (int)ocnt[f]; if (nl > OVCAP) nl = OVCAP;
            for (int e = gw; e < nl; e += 16) {
                int i = ovl[f][e];
                int r = f * NBX + i;
                int ca = classes[r];
                float4 a4 = gbox[r];
                u32 mym = 0;
                if (ln < 32) {
                    u32 p0 = clsb7[f][0][ln], p1 = clsb7[f][1][ln], p2 = clsb7[f][2][ln];
                    u32 m = ((ca & 1) ? p0 : ~p0) & ((ca & 2) ? p1 : ~p1) & ((ca & 4) ? p2 : ~p2);
                    while (m) {
                        int b = __ffs(m) - 1;
                        m &= m - 1;
                        if (iou_ge(a4, gbox[(f + 1) * NBX + ln * 32 + b])) mym |= 1u << b;
                    }
                }
                int cnt_ln = __popc(mym);
                int inc = cnt_ln;
                for (int off = 1; off < 64; off <<= 1) {
                    int v = __shfl_up(inc, off);
                    if (ln >= off) inc += v;
                }
                int deg = __shfl(inc, 63);
                int base_excl = inc - cnt_ln;
                u32 enc = 0; int offw = 0;
                if (ln == 0) {
                    if (deg > 1022) enc = RESCAN_ENC;
                    else {
                        offw = (int)atomicAdd(&pool_top, (u32)((deg + 3) & ~3));
                        if (offw + deg > POOLCAP) enc = RESCAN_ENC;
                        else enc = (3u << 30) | ((u32)(offw >> 2) << 20) |
                                   ((u32)deg << 10) | (u32)deg;
                    }
                    csr[r] = enc;
                }
                u32 encb = __shfl(enc, 0);
                offw = __shfl(offw, 0);
                if (((encb >> 10) & 1023) != 1023 && ln < 32) {
                    u32 m = mym; int idx = base_excl;
                    while (m) {
                        int b = __ffs(m) - 1;
                        m &= m - 1;
                        pool[offw + idx++] = (u16)(ln * 32 + b);
                    }
                }
            }
        }
    }
    u8 act = 0xFF;   // bit f = active(f, t); thread t owns column t
    __syncthreads();

    // ---- 48 greedy extractions. Invariant: active(f,i) <=> ms[f][i] != NEGV,
    //      and active => ms >= 0 (scores >= 0, best_succ >= 0 inductively). ----
    for (int it = 0; it < MAXS; ++it) {
        ms[7 * NBX + t] = (act & 0x80) ? scores[7 * NBX + t] : NEGV;   // DP init f=7
        __syncthreads();
        for (int f = 6; f >= 0; --f) {                   // backward sweep
            const float* msn = &ms[(f + 1) * NBX];
            int r = f * NBX + t;
            // phase A: inline rows resolved; listed overflow rows -> sentinel
            {
                float v = NEGV;
                if ((act >> f) & 1) {
                    u32 p = csr[r];
                    u32 cnt = p >> 30;
                    u32 pj0 = p & 1023, pj1 = (p >> 10) & 1023;
                    bool ovf = (cnt == 3) && (pj0 == pj1);
                    if (!ovf) {
                        float best = 0.0f;   // == ref max(where(eff, ms_next, 0))
                        if (cnt >= 1) best = fmaxf(best, fmaxf(msn[pj0], 0.0f));
                        if (cnt >= 2) best = fmaxf(best, fmaxf(msn[pj1], 0.0f));
                        if (cnt >= 3) best = fmaxf(best, fmaxf(msn[(p >> 20) & 1023], 0.0f));
                        v = __fadd_rn(scores[r], best);
                    } else if (pj0 != 1023) {
                        v = SENTF;           // listed: wave-cooperative phase B
                    } else {                 // rescan fallback: exact serial scan
                        float best = 0.0f;
                        int ca = classes[r];
                        float4 a4 = gbox[r];
                        for (int w = 0; w < 32; ++w) {
                            u32 p0 = clsb7[f][0][w], p1 = clsb7[f][1][w], p2 = clsb7[f][2][w];
                            u32 m = ((ca & 1) ? p0 : ~p0) & ((ca & 2) ? p1 : ~p1) & ((ca & 4) ? p2 : ~p2);
                            while (m) {
                                int b = __ffs(m) - 1;
                                m &= m - 1;
                                int j = w * 32 + b;
                                float mv = msn[j];
                                if (mv > 0.0f && iou_ge(a4, gbox[(f + 1) * NBX + j]))
                                    best = fmaxf(best, mv);
                            }
                        }
                        v = __fadd_rn(scores[r], best);
                    }
                }
                ms[r] = v;
            }
            __syncthreads();
            // phase B: one wave per listed overflow row
            int nl = (int)ocnt[f]; if (nl > OVCAP) nl = OVCAP;
            if (nl > 0) {
                for (int e = gw; e < nl; e += 16) {
                    int i = ovl[f][e];
                    int rr = f * NBX + i;
                    if (ms[rr] != SENTF) continue;       // inactive this iteration
                    float best = 0.0f;                   // identity of the ref max
                    if (use_pool) {
                        u32 p = csr[rr];
                        int deg = (p >> 10) & 1023;
                        int offw = (int)((p >> 20) & 1023) << 2;
                        for (int q = ln; q < deg; q += 64)
                            best = fmaxf(best, fmaxf(msn[pool[offw + q]], 0.0f));
                    } else if (ln < 32) {
                        int ca = classes[rr];
                        float4 a4 = gbox[rr];
                        u32 p0 = clsb7[f][0][ln], p1 = clsb7[f][1][ln], p2 = clsb7[f][2][ln];
                        u32 m = ((ca & 1) ? p0 : ~p0) & ((ca & 2) ? p1 : ~p1) & ((ca & 4) ? p2 : ~p2);
                        while (m) {
                            int b = __ffs(m) - 1;
                            m &= m - 1;
                            int j = ln * 32 + b;
                            if (iou_ge(a4, gbox[(f + 1) * NBX + j]))
                                best = fmaxf(best, fmaxf(msn[j], 0.0f));
                        }
                    }
                    for (int off = 32; off > 0; off >>= 1)
                        best = fmaxf(best, __shfl_down(best, off));
                    if (ln == 0) ms[rr] = __fadd_rn(scores[rr], best);
                }
                __syncthreads();
            }
        }

        // ---- flat argmax over ms, first-index tie-break (== np.argmax) ----
        float bv = ms[t];
        int bi = t;
        for (int f = 1; f < NFR; ++f) {
            int idx = f * NBX + t;
            float m = ms[idx];
            if (m > bv) { bv = m; bi = idx; }            // per-thread idx asc -> first wins
        }
        for (int off = 32; off > 0; off >>= 1) {
            float ov = __shfl_down(bv, off);
            int   oi = __shfl_down(bi, off);
            if (ov > bv || (ov == bv && oi < bi)) { bv = ov; bi = oi; }
        }
        if (ln == 0) { redv[gw] = bv; redi[gw] = bi; }
        if (t < NFR) sel_sh[t] = -1;
        __syncthreads();
        if (t == 0) {
            float v = redv[0]; int i0 = redi[0];
            for (int w = 1; w < 16; ++w)
                if (redv[w] > v || (redv[w] == v && redi[w] < i0)) { v = redv[w]; i0 = redi[w]; }
            bestval_sh = v;
            fstar_sh = i0 >> 10;
            istar_sh = i0 & (NBX - 1);
        }
        __syncthreads();

        // ---- traceback on wave 0 (all breaks wave-uniform) ----
        if (t < 64) {
            int cur = istar_sh;
            for (int f = fstar_sh; f < NFR; ++f) {
                if (t == 0) sel_sh[f] = cur;
                if (f == 7) break;                    // adj_pad[7] all-zero
                int r = f * NBX + cur;
                u32 p = csr[r];
                u32 cnt = p >> 30;
                u32 pj0 = p & 1023, pj1 = (p >> 10) & 1023;
                bool ovf = (cnt == 3) && (pj0 == pj1);
                const float* msn = &ms[(f + 1) * NBX];
                float tv = TSENT;
                int tj = 1 << 30;
                if (!ovf) {
                    if (t < (int)cnt) {
                        int j = (p >> (10 * t)) & 1023;
                        float m = msn[j];
                        if (m != NEGV) { tv = m; tj = j; }   // m != NEGV <=> act_next
                    }
                } else if (use_pool && pj0 != 1023 && pj0 != 0) {   // pool path
                    int deg = (int)pj1;
                    int offw = (int)((p >> 20) & 1023) << 2;
                    for (int q = t; q < deg; q += 64) {
                        int j = pool[offw + q];
                        float mv = msn[j];
                        if (mv != NEGV && (mv > tv || (mv == tv && j < tj))) { tv = mv; tj = j; }
                    }
                } else if (t < 32) {                  // IoU recompute fallback
                    int ca = classes[r];
                    float4 a4 = gbox[r];
                    u32 p0 = clsb7[f][0][t], p1 = clsb7[f][1][t], p2 = clsb7[f][2][t];
                    u32 m = ((ca & 1) ? p0 : ~p0) & ((ca & 2) ? p1 : ~p1) & ((ca & 4) ? p2 : ~p2);
                    while (m) {
                        int b = __ffs(m) - 1;
                        m &= m - 1;
                        int j = t * 32 + b;
                        float mv = msn[j];
                        if (mv != NEGV && iou_ge(a4, gbox[(f + 1) * NBX + j])) {
                            if (mv > tv || (mv == tv && j < tj)) { tv = mv; tj = j; }
                        }
                    }
                }
                for (int off = 32; off > 0; off >>= 1) {
                    float ov = __shfl_down(tv, off);
                    int   oj = __shfl_down(tj, off);
                    if (ov > tv || (ov == tv && oj < tj)) { tv = ov; tj = oj; }
                }
                tv = __shfl(tv, 0);
                tj = __shfl(tj, 0);
                if (tv < -1.0e37f) break;             // no adj&active succ <=> !has_link
                cur = tj;
            }
        }
        __syncthreads();

        // ---- sequence stats ----
        if (t < NFR) {
            int sj = sel_sh[t];
            if (sj >= 0) {
                seqbox[t] = gbox[t * NBX + sj];
                seqcls[t] = classes[t * NBX + sj];
            }
        }
        if (t == 0) {
            int len = 0;
            float sum = 0.0f;
            for (int f = 0; f < NFR; ++f) {
                int sj = sel_sh[f];
                if (sj >= 0) { ++len; sum = __fadd_rn(sum, scores[f * NBX + sj]); }
            }
            avg_sh = __fdiv_rn(sum, (float)len);      // len >= 1 always
            bool ok = (len > 1) && (bestval_sh > 0.0f);
            valid_sh = (ok && !done_sh) ? 1 : 0;
            if (!ok) done_sh = 1;
        }
        __syncthreads();

        // ---- suppression + out writes (only when valid) ----
        if (valid_sh) {
            for (int f = 0; f < NFR; ++f) {
                int sj = sel_sh[f];
                if (sj < 0) continue;                 // frame_in false
                float4 s4 = seqbox[f];
                if (classes[f * NBX + t] != seqcls[f]) continue;
                float4 b4 = gbox[f * NBX + t];
                float wx = fmaxf(__fsub_rn(fminf(s4.z, b4.z), fmaxf(s4.x, b4.x)), 0.0f);
                float wy = fmaxf(__fsub_rn(fminf(s4.w, b4.w), fmaxf(s4.y, b4.y)), 0.0f);
                float inter = __fmul_rn(wx, wy);
                if (inter > 0.0f) {
                    float sa = __fmul_rn(__fsub_rn(s4.z, s4.x), __fsub_rn(s4.w, s4.y));
                    float ba = __fmul_rn(__fsub_rn(b4.z, b4.x), __fsub_rn(b4.w, b4.y));
                    float den = __fadd_rn(__fsub_rn(__fadd_rn(sa, ba), inter), 1e-8f);
                    if (__fdiv_rn(inter, den) >= 0.2f) act &= (u8)~(1u << f);
                }
            }
            if (t < NFR) {
                int sj = sel_sh[t];
                if (sj >= 0) out[t * NBX + sj] = avg_sh;
            }
        }
        __syncthreads();
        if (done_sh) break;   // uniform; remaining reference iterations are no-ops
    }
}

extern "C" void kernel_launch(void* const* d_in, const int* in_sizes, int n_in,
                              void* d_out, int out_size, void* d_ws, size_t ws_size,
                              hipStream_t stream) {
    const float4* boxes = (const float4*)d_in[0];     // (8,1024,4) float32
    const float* scores = (const float*)d_in[1];      // (8,1024) float32
    const int* classes = (const int*)d_in[2];         // (8,1024) int32
    float* out = (float*)d_out;                       // (8,1024) float32
    u16* pool = (u16*)d_ws;
    const int use_pool = (d_ws != nullptr && ws_size >= (size_t)(POOLCAP * 2)) ? 1 : 0;

    seqnms1024<<<1, 1024, 0, stream>>>(boxes, scores, classes, out, pool, use_pool);
}

// Round 7
// 1076.554 us; speedup vs baseline: 9.4788x; 1.0791x over previous
//
#include <hip/hip_runtime.h>

typedef unsigned int u32;
typedef unsigned short u16;
typedef unsigned char u8;
typedef unsigned long long u64;

#define NFR 8
#define NBX 1024
#define NTOT 8192     // 8*1024
#define NROW 7168     // 7*1024 adjacency rows
#define MAXS 48
#define NEGV -1000000000.0f
#define OVTOT 336     // global listed-overflow slot budget
#define PSTRIDE 64    // pool u16 per listed row: [deg, j0..j_{deg-1}]; deg<=63
#define ENC_PENDING ((3u << 30) | (1022u << 10) | 1022u)
#define ENC_RESCAN  ((3u << 30) | (1023u << 10) | 1023u)

// Exact predicate IoU(a,b) >= 0.2 in f32, _rn ops in the reference's
// association order so -ffp-contract cannot change any compare vs numpy.
// LINKAGE_T == IOU_T == 0.2, so one predicate serves both uses.
__device__ __forceinline__ bool iou_ge(float4 a, float4 b) {
    float wx = fmaxf(__fsub_rn(fminf(a.z, b.z), fmaxf(a.x, b.x)), 0.0f);
    float wy = fmaxf(__fsub_rn(fminf(a.w, b.w), fmaxf(a.y, b.y)), 0.0f);
    float inter = __fmul_rn(wx, wy);
    if (!(inter > 0.0f)) return false;      // iou == 0 can never pass >= 0.2
    float aa = __fmul_rn(__fsub_rn(a.z, a.x), __fsub_rn(a.w, a.y));
    float ab = __fmul_rn(__fsub_rn(b.z, b.x), __fsub_rn(b.w, b.y));
    float den = __fadd_rn(__fsub_rn(__fadd_rn(aa, ab), inter), 1e-8f);
    return __fdiv_rn(inter, den) >= 0.2f;
}

// csr row encoding (u32): top 2 bits = cnt.
//   cnt<=3 inline: (cnt<<30)|(j2<<20)|(j1<<10)|j0, ascending j0<j1<j2 -> j0!=j1.
//   listed overflow: (3<<30)|(slot<<10)|slot, slot<OVTOT (j0==j1 impossible inline)
//   rescan fallback: slot field == 1023 (owner thread does exact serial rescan)
__global__ __launch_bounds__(1024) void seqnms(const float4* __restrict__ gbox,
                                               const float* __restrict__ scores,
                                               const int* __restrict__ classes,
                                               float* __restrict__ out,
                                               u16* __restrict__ pool,
                                               const int use_pool) {
    __shared__ float ms[NTOT];          // 32768 B
    __shared__ u32 csr[NROW];           // 28672 B
    __shared__ u32 clsb7[7][3][32];     // 2688 B: class bitplanes, frames 1..7
    __shared__ u16 ovl[OVTOT];          // 672 B: listed row ids (column index)
    __shared__ u32 ostart[8];           // per-frame slot ranges
    __shared__ u32 ofill[7];
    __shared__ u32 ocnt[7];
    __shared__ u64 ovactw[6];           // 48 B: activity bit per listed slot
    __shared__ float redv[16];
    __shared__ int   redi[16];
    __shared__ int   sel_sh[NFR];
    __shared__ float4 seqbox[NFR];
    __shared__ int   seqcls[NFR];
    __shared__ float avg_sh;
    __shared__ int   valid_sh, done_sh;
    // total ~65.3 KB < 64 KiB limit

    const int t = threadIdx.x, gw = t >> 6, ln = t & 63;

    // register-cache own column (removes global loads from all hot sections)
    float sc[NFR]; int cl[NFR]; float4 bx[NFR];
    for (int f = 0; f < NFR; ++f) {
        sc[f] = scores[f * NBX + t];
        cl[f] = classes[f * NBX + t];
        bx[f] = gbox[f * NBX + t];
        out[f * NBX + t] = sc[f];       // identity part of the reference output
    }
    if (t < 7) { ocnt[t] = 0; ofill[t] = 0; }
    if (t < 6) ovactw[t] = ~0ull;
    if (t == 0) done_sh = 0;

    // ---- class bitplanes for frames 1..7 ----
    if (t < 224) {
        int fr = (t >> 5) + 1, w = t & 31;
        u32 p0 = 0, p1 = 0, p2 = 0;
        for (int b = 0; b < 32; ++b) {
            int c = classes[fr * NBX + w * 32 + b];
            p0 |= (u32)(c & 1) << b;
            p1 |= (u32)((c >> 1) & 1) << b;
            p2 |= (u32)((c >> 2) & 1) << b;
        }
        clsb7[fr - 1][0][w] = p0; clsb7[fr - 1][1][w] = p1; clsb7[fr - 1][2][w] = p2;
    }
    __syncthreads();

    // ---- CSR pass 1: inline rows + overflow counting (ascending j order) ----
    for (int f = 0; f < 7; ++f) {
        int r = f * NBX + t;
        int ca = cl[f];
        float4 a4 = bx[f];
        u32 cnt = 0, j0 = 0, j1 = 0, j2 = 0;
        for (int w = 0; w < 32; ++w) {
            u32 p0 = clsb7[f][0][w], p1 = clsb7[f][1][w], p2 = clsb7[f][2][w];
            u32 m = ((ca & 1) ? p0 : ~p0) & ((ca & 2) ? p1 : ~p1) & ((ca & 4) ? p2 : ~p2);
            while (m) {
                int b = __ffs(m) - 1;
                m &= m - 1;
                int j = w * 32 + b;
                if (iou_ge(a4, gbox[(f + 1) * NBX + j])) {
                    if (cnt == 0) j0 = j; else if (cnt == 1) j1 = j; else if (cnt == 2) j2 = j;
                    ++cnt;
                }
            }
        }
        if (cnt <= 3) csr[r] = (cnt << 30) | (j2 << 20) | (j1 << 10) | j0;
        else { atomicAdd(&ocnt[f], 1u); csr[r] = ENC_PENDING; }
    }
    __syncthreads();
    if (t == 0) {
        u32 s = 0;
        for (int f = 0; f < 7; ++f) { ostart[f] = s; s += ocnt[f]; }
        ostart[7] = s;
    }
    __syncthreads();
    // ---- CSR pass 1b: assign global slots ----
    for (int f = 0; f < 7; ++f) {
        int r = f * NBX + t;
        if (csr[r] == ENC_PENDING) {
            u32 slot = ostart[f] + atomicAdd(&ofill[f], 1u);
            if (slot < OVTOT) { ovl[slot] = (u16)t; csr[r] = (3u << 30) | (slot << 10) | slot; }
            else csr[r] = ENC_RESCAN;
        }
    }
    __syncthreads();
    // ---- CSR pass 2: materialize full neighbor lists into the d_ws pool ----
    if (use_pool) {
        int total = (int)ostart[7]; if (total > OVTOT) total = OVTOT;
        for (int s = gw; s < total; s += 16) {
            int f = 0;
            while (s >= (int)ostart[f + 1]) ++f;
            int i = ovl[s];
            int r = f * NBX + i;
            int ca = classes[r];
            float4 a4 = gbox[r];
            u32 mym = 0;
            if (ln < 32) {
                u32 p0 = clsb7[f][0][ln], p1 = clsb7[f][1][ln], p2 = clsb7[f][2][ln];
                u32 m = ((ca & 1) ? p0 : ~p0) & ((ca & 2) ? p1 : ~p1) & ((ca & 4) ? p2 : ~p2);
                while (m) {
                    int b = __ffs(m) - 1;
                    m &= m - 1;
                    if (iou_ge(a4, gbox[(f + 1) * NBX + ln * 32 + b])) mym |= 1u << b;
                }
            }
            int c = __popc(mym), inc = c;
            for (int off = 1; off < 64; off <<= 1) {
                int v = __shfl_up(inc, off);
                if (ln >= off) inc += v;
            }
            int deg = __shfl(inc, 63);
            int base = inc - c;
            if (deg <= PSTRIDE - 1) {
                if (ln == 0) pool[s * PSTRIDE] = (u16)deg;
                if (ln < 32) {
                    u32 m = mym; int idx = base;
                    while (m) {
                        int b = __ffs(m) - 1;
                        m &= m - 1;
                        pool[s * PSTRIDE + 1 + idx++] = (u16)(ln * 32 + b);  // ascending j
                    }
                }
            } else if (ln == 0) csr[r] = ENC_RESCAN;
        }
    }
    u8 act = 0xFF;                       // bit f = active(f, t)
    ms[7 * NBX + t] = sc[7];             // initial DP frame-7 (all active)
    __syncthreads();

    // ---- 48 greedy extractions. Invariant: active(f,i) <=> ms[f][i] != NEGV,
    //      and active => ms >= 0. 10 barriers/iteration. ----
    for (int it = 0; it < MAXS; ++it) {
        for (int f = 6; f >= 0; --f) {                   // DP backward sweep
            const float* msn = &ms[(f + 1) * NBX];
            int r = f * NBX + t;
            u32 p = csr[r];
            u32 cnt = p >> 30, pj0 = p & 1023, pj1 = (p >> 10) & 1023;
            bool listed = (cnt == 3) && (pj0 == pj1);
            if (!listed) {                               // inline rows (common)
                float v = NEGV;
                if ((act >> f) & 1) {
                    float best = 0.0f;   // == ref max(where(eff, ms_next, 0))
                    if (cnt >= 1) best = fmaxf(best, fmaxf(msn[pj0], 0.0f));
                    if (cnt >= 2) best = fmaxf(best, fmaxf(msn[pj1], 0.0f));
                    if (cnt >= 3) best = fmaxf(best, fmaxf(msn[(p >> 20) & 1023], 0.0f));
                    v = __fadd_rn(sc[f], best);
                }
                ms[r] = v;
            } else if (pj0 == 1023) {                    // rescan fallback (rare)
                float v = NEGV;
                if ((act >> f) & 1) {
                    float best = 0.0f;
                    int ca = cl[f];
                    float4 a4 = bx[f];
                    for (int w = 0; w < 32; ++w) {
                        u32 p0 = clsb7[f][0][w], p1 = clsb7[f][1][w], p2 = clsb7[f][2][w];
                        u32 m = ((ca & 1) ? p0 : ~p0) & ((ca & 2) ? p1 : ~p1) & ((ca & 4) ? p2 : ~p2);
                        while (m) {
                            int b = __ffs(m) - 1;
                            m &= m - 1;
                            int j = w * 32 + b;
                            float mv = msn[j];
                            if (mv > 0.0f && iou_ge(a4, gbox[(f + 1) * NBX + j]))
                                best = fmaxf(best, mv);
                        }
                    }
                    v = __fadd_rn(sc[f], best);
                }
                ms[r] = v;
            }
            // listed rows with valid slot: written ONLY by phase B below (disjoint)
            int s0 = (int)ostart[f], s1 = (int)ostart[f + 1];
            if (s1 > OVTOT) s1 = OVTOT;
            for (int s = s0 + gw; s < s1; s += 16) {     // one wave per listed row
                int i = ovl[s];
                int rr = f * NBX + i;
                if ((csr[rr] & 1023) == 1023) continue;  // converted to rescan; owner wrote
                bool active = (ovactw[s >> 6] >> (s & 63)) & 1ull;
                float res = NEGV;
                if (active) {
                    float best = 0.0f;
                    if (use_pool) {
                        int deg = pool[s * PSTRIDE];
                        for (int q = 1 + ln; q <= deg; q += 64)
                            best = fmaxf(best, fmaxf(msn[pool[s * PSTRIDE + q]], 0.0f));
                    } else if (ln < 32) {
                        int ca = classes[rr];
                        float4 a4 = gbox[rr];
                        u32 p0 = clsb7[f][0][ln], p1 = clsb7[f][1][ln], p2 = clsb7[f][2][ln];
                        u32 m = ((ca & 1) ? p0 : ~p0) & ((ca & 2) ? p1 : ~p1) & ((ca & 4) ? p2 : ~p2);
                        while (m) {
                            int b = __ffs(m) - 1;
                            m &= m - 1;
                            int j = ln * 32 + b;
                            if (iou_ge(a4, gbox[(f + 1) * NBX + j]))
                                best = fmaxf(best, fmaxf(msn[j], 0.0f));
                        }
                    }
                    for (int off = 32; off > 0; off >>= 1)
                        best = fmaxf(best, __shfl_down(best, off));
                    res = __fadd_rn(scores[rr], best);
                }
                if (ln == 0) ms[rr] = res;
            }
            __syncthreads();
        }

        // ---- argmax partial: per-thread 8 reads + per-wave reduce ----
        float bv = ms[t];
        int bi = t;
        for (int f = 1; f < NFR; ++f) {
            int idx = f * NBX + t;
            float m = ms[idx];
            if (m > bv) { bv = m; bi = idx; }            // idx ascending -> first wins
        }
        for (int off = 32; off > 0; off >>= 1) {
            float ov = __shfl_down(bv, off);
            int   oi = __shfl_down(bi, off);
            if (ov > bv || (ov == bv && oi < bi)) { bv = ov; bi = oi; }
        }
        if (ln == 0) { redv[gw] = bv; redi[gw] = bi; }
        __syncthreads();

        // ---- wave 0: final reduce + traceback + stats (one section) ----
        if (t < 64) {
            float v = (ln < 16) ? redv[ln] : -3.0e38f;
            int i0 = (ln < 16) ? redi[ln] : 0x7fffffff;
            for (int off = 8; off > 0; off >>= 1) {
                float ov = __shfl_down(v, off);
                int   oi = __shfl_down(i0, off);
                if (ov > v || (ov == v && oi < i0)) { v = ov; i0 = oi; }
            }
            v = __shfl(v, 0);
            i0 = __shfl(i0, 0);
            const float bestval = v;
            const int fstar = i0 >> 10, istar = i0 & (NBX - 1);
            if (ln < NFR) sel_sh[ln] = -1;
            int cur = istar;
            for (int f = fstar; f < NFR; ++f) {          // all breaks wave-uniform
                if (ln == 0) sel_sh[f] = cur;
                if (f == 7) break;                       // adj_pad[7] all-zero
                int r = f * NBX + cur;
                u32 p = csr[r];
                u32 cnt = p >> 30, pj0 = p & 1023, pj1 = (p >> 10) & 1023;
                bool listed = (cnt == 3) && (pj0 == pj1);
                const float* msn = &ms[(f + 1) * NBX];
                float tv = -3.0e38f;
                int tj = 0x7fffffff;
                if (!listed) {
                    if (ln < (int)cnt) {
                        int j = (p >> (10 * ln)) & 1023;
                        float m = msn[j];
                        if (m != NEGV) { tv = m; tj = j; }   // m != NEGV <=> act_next
                    }
                } else if (pj0 != 1023 && use_pool) {
                    int s = (int)pj0;
                    int deg = pool[s * PSTRIDE];
                    for (int q = 1 + ln; q <= deg; q += 64) {
                        int j = pool[s * PSTRIDE + q];
                        float m = msn[j];
                        if (m != NEGV && (m > tv || (m == tv && j < tj))) { tv = m; tj = j; }
                    }
                } else if (ln < 32) {                    // IoU recompute fallback
                    int ca = classes[r];
                    float4 a4 = gbox[r];
                    u32 p0 = clsb7[f][0][ln], p1 = clsb7[f][1][ln], p2 = clsb7[f][2][ln];
                    u32 m = ((ca & 1) ? p0 : ~p0) & ((ca & 2) ? p1 : ~p1) & ((ca & 4) ? p2 : ~p2);
                    while (m) {
                        int b = __ffs(m) - 1;
                        m &= m - 1;
                        int j = ln * 32 + b;
                        float mv = msn[j];
                        if (mv != NEGV && iou_ge(a4, gbox[(f + 1) * NBX + j])) {
                            if (mv > tv || (mv == tv && j < tj)) { tv = mv; tj = j; }
                        }
                    }
                }
                for (int off = 32; off > 0; off >>= 1) {
                    float ov = __shfl_down(tv, off);
                    int   oj = __shfl_down(tj, off);
                    if (ov > tv || (ov == tv && oj < tj)) { tv = ov; tj = oj; }
                }
                tv = __shfl(tv, 0);
                tj = __shfl(tj, 0);
                if (tv < -1.0e37f) break;                // !has_link
                cur = tj;
            }
            // stats: 8-lane parallel loads + tree reduce (avg is output-only;
            // control flow uses len/bestval which are exact)
            float sv = 0.0f;
            int c = 0;
            if (ln < NFR) {
                int sj = sel_sh[ln];
                if (sj >= 0) {
                    sv = scores[ln * NBX + sj];
                    c = 1;
                    seqbox[ln] = gbox[ln * NBX + sj];
                    seqcls[ln] = classes[ln * NBX + sj];
                }
            }
            for (int off = 4; off > 0; off >>= 1) {
                sv = __fadd_rn(sv, __shfl_down(sv, off));
                c += __shfl_down(c, off);
            }
            if (ln == 0) {
                avg_sh = __fdiv_rn(sv, (float)c);        // c >= 1 always
                bool ok = (c > 1) && (bestval > 0.0f);
                valid_sh = (ok && !done_sh) ? 1 : 0;
                if (!ok) done_sh = 1;
            }
        }
        __syncthreads();

        // ---- suppression + state updates + out writes (only when valid) ----
        if (valid_sh) {
            for (int f = 0; f < NFR; ++f) {
                int sj = sel_sh[f];
                if (sj < 0) continue;                    // frame_in false
                if (cl[f] != seqcls[f]) continue;
                float4 s4 = seqbox[f], b4 = bx[f];
                float wx = fmaxf(__fsub_rn(fminf(s4.z, b4.z), fmaxf(s4.x, b4.x)), 0.0f);
                float wy = fmaxf(__fsub_rn(fminf(s4.w, b4.w), fmaxf(s4.y, b4.y)), 0.0f);
                float inter = __fmul_rn(wx, wy);
                if (inter > 0.0f) {
                    float sa = __fmul_rn(__fsub_rn(s4.z, s4.x), __fsub_rn(s4.w, s4.y));
                    float ba = __fmul_rn(__fsub_rn(b4.z, b4.x), __fsub_rn(b4.w, b4.y));
                    float den = __fadd_rn(__fsub_rn(__fadd_rn(sa, ba), inter), 1e-8f);
                    if (__fdiv_rn(inter, den) >= 0.2f) act &= (u8)~(1u << f);
                }
            }
            // publish activity for owned listed rows (phase B reads ovactw)
            for (int f = 0; f < 7; ++f) {
                u32 p = csr[f * NBX + t];
                u32 cnt = p >> 30, pj0 = p & 1023, pj1 = (p >> 10) & 1023;
                if (cnt == 3 && pj0 == pj1 && pj0 != 1023) {
                    u64 mask = 1ull << (pj0 & 63);
                    if ((act >> f) & 1) atomicOr(&ovactw[pj0 >> 6], mask);
                    else                atomicAnd(&ovactw[pj0 >> 6], ~mask);
                }
            }
            ms[7 * NBX + t] = (act & 0x80) ? sc[7] : NEGV;   // next iter's DP init
            if (t < NFR) {
                int sj = sel_sh[t];
                if (sj >= 0) out[t * NBX + sj] = avg_sh;
            }
        }
        __syncthreads();
        if (done_sh) break;   // uniform; remaining reference iterations are no-ops
    }
}

extern "C" void kernel_launch(void* const* d_in, const int* in_sizes, int n_in,
                              void* d_out, int out_size, void* d_ws, size_t ws_size,
                              hipStream_t stream) {
    const float4* boxes = (const float4*)d_in[0];     // (8,1024,4) float32
    const float* scores = (const float*)d_in[1];      // (8,1024) float32
    const int* classes = (const int*)d_in[2];         // (8,1024) int32
    float* out = (float*)d_out;                       // (8,1024) float32
    u16* pool = (u16*)d_ws;
    const int use_pool =
        (d_ws != nullptr && ws_size >= (size_t)(OVTOT * PSTRIDE * 2)) ? 1 : 0;

    seqnms<<<1, 1024, 0, stream>>>(boxes, scores, classes, out, pool, use_pool);
}

// Round 8
// 949.037 us; speedup vs baseline: 10.7525x; 1.1344x over previous
//
#include <hip/hip_runtime.h>

typedef unsigned int u32;
typedef unsigned short u16;
typedef unsigned char u8;

#define NFR 8
#define NBX 1024
#define NTOT 8192     // 8*1024
#define NROW 7168     // 7*1024 adjacency rows
#define MAXS 48
#define NEGV -1000000000.0f
#define OVTOT 256     // listed-overflow slot budget (expected demand ~15-100)
#define PSTRIDE 64    // pool u16 per listed row: [deg, j0..j_{deg-1}], deg<=63
#define DEG_RECOMP 0xFFFF
#define ENC_PENDING ((3u << 30) | (1022u << 10) | 1022u)
#define ENC_RESCAN  ((3u << 30) | (1023u << 10) | 1023u)

// Exact predicate IoU(a,b) >= 0.2 in f32, _rn ops in the reference's
// association order (area_a from 'a' first) so -ffp-contract cannot change
// any compare vs numpy. LINKAGE_T == IOU_T == 0.2: one predicate, both uses.
__device__ __forceinline__ bool iou_ge(float4 a, float4 b) {
    float wx = fmaxf(__fsub_rn(fminf(a.z, b.z), fmaxf(a.x, b.x)), 0.0f);
    float wy = fmaxf(__fsub_rn(fminf(a.w, b.w), fmaxf(a.y, b.y)), 0.0f);
    float inter = __fmul_rn(wx, wy);
    if (!(inter > 0.0f)) return false;      // iou == 0 can never pass >= 0.2
    float aa = __fmul_rn(__fsub_rn(a.z, a.x), __fsub_rn(a.w, a.y));
    float ab = __fmul_rn(__fsub_rn(b.z, b.x), __fsub_rn(b.w, b.y));
    float den = __fadd_rn(__fsub_rn(__fadd_rn(aa, ab), inter), 1e-8f);
    return __fdiv_rn(inter, den) >= 0.2f;
}

// csr row encoding (u32): top 2 bits = cnt.
//   inline (cnt<=3): (cnt<<30)|(j2<<20)|(j1<<10)|j0, ascending -> j0!=j1 if cnt==3
//   listed overflow: (3<<30)|(slot<<10)|slot, slot < OVTOT
//   rescan fallback: slot field == 1023 (slot budget exhausted; ~never)
__global__ __launch_bounds__(1024) void seqnms(const float4* __restrict__ gbox,
                                               const float* __restrict__ scores,
                                               const int* __restrict__ classes,
                                               float* __restrict__ out,
                                               u16* __restrict__ pool,
                                               const int use_pool) {
    // declarations ordered by alignment (LDS total ~65.3 KB <= 65536)
    __shared__ float4 seqbox[NFR];      // 128
    __shared__ float ms[NTOT];          // 32768
    __shared__ u32 csr[NROW];           // 28672
    __shared__ u32 clsb7[7][3][32];     // 2688: class bitplanes, frames 1..7
    __shared__ u32 ostart[8];           // 32
    __shared__ u32 ofill[7];            // 28
    __shared__ u32 ocnt[7];             // 28
    __shared__ float redv[16];          // 64
    __shared__ int   redi[16];          // 64
    __shared__ int   sel_sh[NFR];       // 32
    __shared__ int   seqcls[NFR];       // 32
    __shared__ float avg_sh;
    __shared__ int   valid_sh, done_sh;
    __shared__ u16 ovl[OVTOT];          // 512: listed row ids (column index)
    __shared__ u8  ovact[OVTOT];        // 256: activity, one unique owner each

    const int t = threadIdx.x, gw = t >> 6, ln = t & 63;

    // -- register-cache own column; small unrolled loops -> true VGPRs --
    float psc[NFR]; int pcl[NFR]; float4 pbx[NFR];
    #pragma unroll
    for (int f = 0; f < NFR; ++f) {
        psc[f] = scores[f * NBX + t];
        pcl[f] = classes[f * NBX + t];
        pbx[f] = gbox[f * NBX + t];
        out[f * NBX + t] = psc[f];      // identity part of the reference output
    }
    if (t < 7) { ocnt[t] = 0; ofill[t] = 0; }
    if (t < OVTOT) ovact[t] = 1;
    if (t == 0) done_sh = 0;

    // ---- class bitplanes for frames 1..7 ----
    if (t < 224) {
        int fr = (t >> 5) + 1, w = t & 31;
        u32 p0 = 0, p1 = 0, p2 = 0;
        for (int b = 0; b < 32; ++b) {
            int c = classes[fr * NBX + w * 32 + b];
            p0 |= (u32)(c & 1) << b;
            p1 |= (u32)((c >> 1) & 1) << b;
            p2 |= (u32)((c >> 2) & 1) << b;
        }
        clsb7[fr - 1][0][w] = p0; clsb7[fr - 1][1][w] = p1; clsb7[fr - 1][2][w] = p2;
    }
    __syncthreads();

    // ---- CSR pass 1: inline rows + overflow counting (ascending j) ----
    for (int f = 0; f < 7; ++f) {
        int r = f * NBX + t;
        int ca = pcl[f];
        float4 a4 = pbx[f];
        u32 cnt = 0, j0 = 0, j1 = 0, j2 = 0;
        for (int w = 0; w < 32; ++w) {
            u32 q0 = clsb7[f][0][w], q1 = clsb7[f][1][w], q2 = clsb7[f][2][w];
            u32 m = ((ca & 1) ? q0 : ~q0) & ((ca & 2) ? q1 : ~q1) & ((ca & 4) ? q2 : ~q2);
            while (m) {
                int b = __ffs(m) - 1;
                m &= m - 1;
                int j = w * 32 + b;
                if (iou_ge(a4, gbox[(f + 1) * NBX + j])) {
                    if (cnt == 0) j0 = j; else if (cnt == 1) j1 = j; else if (cnt == 2) j2 = j;
                    ++cnt;
                }
            }
        }
        if (cnt <= 3) csr[r] = (cnt << 30) | (j2 << 20) | (j1 << 10) | j0;
        else { atomicAdd(&ocnt[f], 1u); csr[r] = ENC_PENDING; }
    }
    __syncthreads();
    if (t == 0) {
        u32 s = 0;
        for (int f = 0; f < 7; ++f) { ostart[f] = s; s += ocnt[f]; }
        ostart[7] = s;
    }
    __syncthreads();
    // ---- CSR pass 1b: assign slots ----
    for (int f = 0; f < 7; ++f) {
        int r = f * NBX + t;
        if (csr[r] == ENC_PENDING) {
            u32 slot = ostart[f] + atomicAdd(&ofill[f], 1u);
            if (slot < OVTOT) { ovl[slot] = (u16)t; csr[r] = (3u << 30) | (slot << 10) | slot; }
            else csr[r] = ENC_RESCAN;
        }
    }
    __syncthreads();
    // ---- CSR pass 2: materialize neighbor lists into the d_ws pool ----
    if (use_pool) {
        int total = (int)ostart[7]; if (total > OVTOT) total = OVTOT;
        for (int s = gw; s < total; s += 16) {
            int f = 0;
            while (s >= (int)ostart[f + 1]) ++f;
            int i = ovl[s];
            int ca = classes[f * NBX + i];
            float4 a4 = gbox[f * NBX + i];
            u32 mym = 0;
            if (ln < 32) {
                u32 q0 = clsb7[f][0][ln], q1 = clsb7[f][1][ln], q2 = clsb7[f][2][ln];
                u32 m = ((ca & 1) ? q0 : ~q0) & ((ca & 2) ? q1 : ~q1) & ((ca & 4) ? q2 : ~q2);
                while (m) {
                    int b = __ffs(m) - 1;
                    m &= m - 1;
                    if (iou_ge(a4, gbox[(f + 1) * NBX + ln * 32 + b])) mym |= 1u << b;
                }
            }
            int c = __popc(mym), inc = c;
            for (int off = 1; off < 64; off <<= 1) {
                int v = __shfl_up(inc, off);
                if (ln >= off) inc += v;
            }
            int deg = __shfl(inc, 63);
            int base = inc - c;
            if (deg <= PSTRIDE - 1) {
                if (ln == 0) pool[s * PSTRIDE] = (u16)deg;
                if (ln < 32) {
                    u32 m = mym; int idx = base;
                    while (m) {
                        int b = __ffs(m) - 1;
                        m &= m - 1;
                        pool[s * PSTRIDE + 1 + idx++] = (u16)(ln * 32 + b); // ascending j
                    }
                }
            } else if (ln == 0) pool[s * PSTRIDE] = (u16)DEG_RECOMP; // coop recompute
        }
    }
    __syncthreads();

    // -- iteration-invariant per-thread registers --
    u32 pc[7]; u32 lmask = 0;
    #pragma unroll
    for (int f = 0; f < 7; ++f) {
        u32 p = csr[f * NBX + t];
        pc[f] = p;
        if ((p >> 30) == 3u && (p & 1023) == ((p >> 10) & 1023) && (p & 1023) != 1023)
            lmask |= 1u << f;               // listed: phase B owns the ms write
    }
    int os[8];                              // wave-uniform -> SGPRs
    #pragma unroll
    for (int f = 0; f < 8; ++f) {
        int v = (int)ostart[f]; if (v > OVTOT) v = OVTOT;
        os[f] = __builtin_amdgcn_readfirstlane(v);
    }
    u32 act = 0xFF;                         // bit f = active(f, t)
    float ms7 = psc[7];
    ms[7 * NBX + t] = ms7;
    __syncthreads();

    // ---- 48 greedy extractions. Invariant: active(f,i) <=> ms[f][i] != NEGV,
    //      active => ms >= 0. 10 barriers/iter, short chains. ----
    for (int it = 0; it < MAXS; ++it) {
        float bv = ms7; int bi = 7 * NBX + t;   // register argmax tracking
        #pragma unroll
        for (int f = 6; f >= 0; --f) {
            const float* msn = &ms[(f + 1) * NBX];
            const u32 p = pc[f];
            const u32 c = p >> 30, j0 = p & 1023, j1 = (p >> 10) & 1023;
            const bool ovf = (c == 3u) && (j0 == j1);
            const int r = f * NBX + t;
            if (!ovf) {                          // inline rows (vast majority)
                float v = NEGV;
                if ((act >> f) & 1) {
                    float best = 0.0f;           // == ref max(where(eff, ms_next, 0))
                    if (c >= 1) best = fmaxf(best, fmaxf(msn[j0], 0.0f));
                    if (c >= 2) best = fmaxf(best, fmaxf(msn[j1], 0.0f));
                    if (c >= 3) best = fmaxf(best, fmaxf(msn[(p >> 20) & 1023], 0.0f));
                    v = __fadd_rn(psc[f], best);
                }
                ms[r] = v;
                if (v > bv || (v == bv && r < bi)) { bv = v; bi = r; }
            } else if (j0 == 1023) {             // rescan (slot exhausted; ~never)
                float v = NEGV;
                if ((act >> f) & 1) {
                    float best = 0.0f;
                    int ca = pcl[f]; float4 a4 = pbx[f];
                    for (int w = 0; w < 32; ++w) {
                        u32 q0 = clsb7[f][0][w], q1 = clsb7[f][1][w], q2 = clsb7[f][2][w];
                        u32 m = ((ca & 1) ? q0 : ~q0) & ((ca & 2) ? q1 : ~q1) & ((ca & 4) ? q2 : ~q2);
                        while (m) {
                            int b = __ffs(m) - 1;
                            m &= m - 1;
                            int j = w * 32 + b;
                            float mv = msn[j];
                            if (mv > 0.0f && iou_ge(a4, gbox[(f + 1) * NBX + j]))
                                best = fmaxf(best, mv);
                        }
                    }
                    v = __fadd_rn(psc[f], best);
                }
                ms[r] = v;
                if (v > bv || (v == bv && r < bi)) { bv = v; bi = r; }
            }
            // phase B: listed rows, one wave each (pure-register guard)
            {
                const int s1 = os[f + 1];
                for (int s = os[f] + gw; s < s1; s += 16) {
                    int i = ovl[s];
                    int rr = f * NBX + i;
                    bool actv = ovact[s] != 0;   // wave-uniform
                    float best = 0.0f;
                    if (actv) {
                        int deg = use_pool ? (int)pool[s * PSTRIDE] : (int)DEG_RECOMP;
                        if (deg != (int)DEG_RECOMP) {
                            for (int q = ln; q < deg; q += 64)
                                best = fmaxf(best, fmaxf(msn[pool[s * PSTRIDE + 1 + q]], 0.0f));
                        } else {
                            int ca = classes[rr]; float4 a4 = gbox[rr];
                            if (ln < 32) {
                                u32 q0 = clsb7[f][0][ln], q1 = clsb7[f][1][ln], q2 = clsb7[f][2][ln];
                                u32 m = ((ca & 1) ? q0 : ~q0) & ((ca & 2) ? q1 : ~q1) & ((ca & 4) ? q2 : ~q2);
                                while (m) {
                                    int b = __ffs(m) - 1;
                                    m &= m - 1;
                                    int j = ln * 32 + b;
                                    if (iou_ge(a4, gbox[(f + 1) * NBX + j]))
                                        best = fmaxf(best, fmaxf(msn[j], 0.0f));
                                }
                            }
                        }
                        #pragma unroll
                        for (int off = 32; off > 0; off >>= 1)
                            best = fmaxf(best, __shfl_down(best, off));
                    }
                    if (ln == 0) ms[rr] = actv ? __fadd_rn(scores[rr], best) : NEGV;
                }
            }
            __syncthreads();
        }

        // ---- listed fix-up (rare) + per-wave argmax reduce ----
        #pragma unroll
        for (int f = 0; f < 7; ++f) if ((lmask >> f) & 1) {
            int r = f * NBX + t; float v = ms[r];
            if (v > bv || (v == bv && r < bi)) { bv = v; bi = r; }
        }
        #pragma unroll
        for (int off = 32; off > 0; off >>= 1) {
            float ov = __shfl_down(bv, off); int oi = __shfl_down(bi, off);
            if (ov > bv || (ov == bv && oi < bi)) { bv = ov; bi = oi; }
        }
        if (ln == 0) { redv[gw] = bv; redi[gw] = bi; }
        __syncthreads();

        // ---- wave 0: final reduce + traceback + stats ----
        if (t < 64) {
            float v = (ln < 16) ? redv[ln] : -3.0e38f;
            int i0 = (ln < 16) ? redi[ln] : 0x7fffffff;
            #pragma unroll
            for (int off = 8; off > 0; off >>= 1) {
                float ov = __shfl_down(v, off); int oi = __shfl_down(i0, off);
                if (ov > v || (ov == v && oi < i0)) { v = ov; i0 = oi; }
            }
            v = __shfl(v, 0); i0 = __shfl(i0, 0);
            const float bestval = v;
            const int fstar = i0 >> 10, istar = i0 & (NBX - 1);
            if (ln < NFR) sel_sh[ln] = -1;
            int cur = istar;
            for (int f = fstar; f < NFR; ++f) {       // all breaks wave-uniform
                if (ln == 0) sel_sh[f] = cur;
                if (f == 7) break;                    // adj_pad[7] all-zero
                u32 p = csr[f * NBX + cur];
                u32 c = p >> 30, j0 = p & 1023, j1 = (p >> 10) & 1023;
                const float* msn = &ms[(f + 1) * NBX];
                if (!((c == 3u) && (j0 == j1))) {     // inline: all-lane redundant
                    float tb = -3.0e38f; int tj = -1; // ascending j + strict > ==
                    if (c >= 1) { float m = msn[j0]; if (m != NEGV) { tb = m; tj = (int)j0; } }
                    if (c >= 2) { float m = msn[j1]; if (m != NEGV && m > tb) { tb = m; tj = (int)j1; } }
                    if (c >= 3) { int j2 = (p >> 20) & 1023; float m = msn[j2];
                                  if (m != NEGV && m > tb) { tb = m; tj = j2; } }
                    if (tj < 0) break;                // !has_link
                    cur = tj;
                } else {                              // listed / rescan: cooperative
                    float tv = -3.0e38f; int tj = 0x7fffffff;
                    bool recomp = true;
                    if (j0 != 1023 && use_pool) {
                        int s = (int)j0;
                        int deg = (int)pool[s * PSTRIDE];
                        if (deg != (int)DEG_RECOMP) {
                            recomp = false;
                            for (int q = ln; q < deg; q += 64) {
                                int j = (int)pool[s * PSTRIDE + 1 + q];
                                float m = msn[j];
                                if (m != NEGV && (m > tv || (m == tv && j < tj))) { tv = m; tj = j; }
                            }
                        }
                    }
                    if (recomp) {
                        int ca = classes[f * NBX + cur]; float4 a4 = gbox[f * NBX + cur];
                        if (ln < 32) {
                            u32 q0 = clsb7[f][0][ln], q1 = clsb7[f][1][ln], q2 = clsb7[f][2][ln];
                            u32 m = ((ca & 1) ? q0 : ~q0) & ((ca & 2) ? q1 : ~q1) & ((ca & 4) ? q2 : ~q2);
                            while (m) {
                                int b = __ffs(m) - 1;
                                m &= m - 1;
                                int j = ln * 32 + b;
                                float mv = msn[j];
                                if (mv != NEGV && iou_ge(a4, gbox[(f + 1) * NBX + j])) {
                                    if (mv > tv || (mv == tv && j < tj)) { tv = mv; tj = j; }
                                }
                            }
                        }
                    }
                    #pragma unroll
                    for (int off = 32; off > 0; off >>= 1) {
                        float ov = __shfl_down(tv, off); int oj = __shfl_down(tj, off);
                        if (ov > tv || (ov == tv && oj < tj)) { tv = ov; tj = oj; }
                    }
                    tv = __shfl(tv, 0); tj = __shfl(tj, 0);
                    if (tv < -1.0e37f) break;         // !has_link
                    cur = tj;
                }
            }
            // stats (avg is output-only; len/bestval steering is exact)
            float sv = 0.0f; int cc = 0;
            if (ln < NFR) {
                int sj = sel_sh[ln];
                if (sj >= 0) {
                    sv = scores[ln * NBX + sj]; cc = 1;
                    seqbox[ln] = gbox[ln * NBX + sj];
                    seqcls[ln] = classes[ln * NBX + sj];
                }
            }
            #pragma unroll
            for (int off = 4; off > 0; off >>= 1) {
                sv = __fadd_rn(sv, __shfl_down(sv, off));
                cc += __shfl_down(cc, off);
            }
            if (ln == 0) {
                avg_sh = __fdiv_rn(sv, (float)cc);    // cc >= 1 always
                bool ok = (cc > 1) && (bestval > 0.0f);
                valid_sh = (ok && !done_sh) ? 1 : 0;
                if (!ok) done_sh = 1;
            }
        }
        __syncthreads();

        // ---- suppression + state publish + out writes (only when valid) ----
        if (valid_sh) {
            #pragma unroll
            for (int f = 0; f < NFR; ++f) {
                int sj = sel_sh[f];
                if (sj < 0) continue;                 // frame_in false
                if (pcl[f] != seqcls[f]) continue;
                if (iou_ge(seqbox[f], pbx[f])) act &= ~(1u << f);
            }
            #pragma unroll
            for (int f = 0; f < 7; ++f) if ((lmask >> f) & 1)
                ovact[pc[f] & 1023] = (u8)((act >> f) & 1);   // unique owner, no atomic
            ms7 = (act & 0x80) ? psc[7] : NEGV;
            ms[7 * NBX + t] = ms7;                    // next iteration's DP init
            if (t < NFR) {
                int sj = sel_sh[t];
                if (sj >= 0) out[t * NBX + sj] = avg_sh;
            }
        }
        __syncthreads();
        if (done_sh) break;   // uniform; remaining reference iterations are no-ops
    }
}

extern "C" void kernel_launch(void* const* d_in, const int* in_sizes, int n_in,
                              void* d_out, int out_size, void* d_ws, size_t ws_size,
                              hipStream_t stream) {
    const float4* boxes = (const float4*)d_in[0];     // (8,1024,4) float32
    const float* scores = (const float*)d_in[1];      // (8,1024) float32
    const int* classes = (const int*)d_in[2];         // (8,1024) int32
    float* out = (float*)d_out;                       // (8,1024) float32
    u16* pool = (u16*)d_ws;
    const int use_pool =
        (d_ws != nullptr && ws_size >= (size_t)(OVTOT * PSTRIDE * 2)) ? 1 : 0;

    seqnms<<<1, 1024, 0, stream>>>(boxes, scores, classes, out, pool, use_pool);
}